// Round 3
// baseline (264.308 us; speedup 1.0000x reference)
//
#include <hip/hip_runtime.h>
#include <hip/hip_bf16.h>
#include <math.h>

// DiceLoss: B=8, C=19, H=W=512. logits fp32 [B,C,H,W], targets int [B,H,W].
// Round 3: latency-bound fix. Three-phase body (batched float2 loads -> one
// vmcnt wait -> exp/sum -> accumulate), 2 pixels/thread, VGPR budget 128
// (launch_bounds 256,4) so all 19 loads stay in flight. No LDS/atomics in
// the hot loop; counts via ballot (scalar pipe); deterministic partials.

#define CC 19
#define HWBITS 18
#define HHWW (1 << HWBITS)            // 512*512 = 262144
#define NPIX (8 * HHWW)               // 2,097,152
#define NPAIR (NPIX / 2)              // 1,048,576
#define NBLK 1024
#define NTHR 256
#define NITER 4                       // NPAIR / (NBLK*NTHR)
#define IGNORE_IDX 255

__global__ __launch_bounds__(NTHR, 4) void dice_accum(
    const float* __restrict__ logits,
    const int* __restrict__ targets,
    float* __restrict__ part)         // part[NBLK][64]: 0-18 S, 19-37 I, 38-56 cnt
{
    const int tid = blockIdx.x * NTHR + threadIdx.x;

    float accS[CC], accI[CC];
#pragma unroll
    for (int c = 0; c < CC; ++c) { accS[c] = 0.f; accI[c] = 0.f; }
    int cnt[CC];
#pragma unroll
    for (int c = 0; c < CC; ++c) cnt[c] = 0;

#pragma unroll
    for (int it = 0; it < NITER; ++it) {
        const int q = tid + it * (NBLK * NTHR);   // pair index
        const int2 tt = ((const int2*)targets)[q];
        const int b = q >> (HWBITS - 1);
        const int hw2 = q & ((HHWW / 2) - 1);
        const float2* base = (const float2*)logits + (size_t)(b * CC) * (HHWW / 2) + hw2;

        // Phase A: pure load batch — 19 independent dwordx2, single wait after
        float2 x[CC];
#pragma unroll
        for (int c = 0; c < CC; ++c)
            x[c] = base[(size_t)c * (HHWW / 2)];

        // Phase B: exp + per-pixel sums
        float s0 = 0.f, s1 = 0.f;
#pragma unroll
        for (int c = 0; c < CC; ++c) {
            x[c].x = __expf(x[c].x);
            x[c].y = __expf(x[c].y);
            s0 += x[c].x;
            s1 += x[c].y;
        }
        const bool v0 = (tt.x != IGNORE_IDX);
        const bool v1 = (tt.y != IGNORE_IDX);
        const float inv0 = v0 ? __builtin_amdgcn_rcpf(s0) : 0.f;
        const float inv1 = v1 ? __builtin_amdgcn_rcpf(s1) : 0.f;

        // Phase C: accumulate
#pragma unroll
        for (int c = 0; c < CC; ++c) {
            accS[c] = fmaf(x[c].x, inv0, accS[c]);
            accS[c] = fmaf(x[c].y, inv1, accS[c]);
            const bool h0 = (tt.x == c);
            const bool h1 = (tt.y == c);
            accI[c] = fmaf(h0 ? x[c].x : 0.f, inv0, accI[c]);
            accI[c] = fmaf(h1 ? x[c].y : 0.f, inv1, accI[c]);
            cnt[c] += (int)__popcll(__ballot(h0)) + (int)__popcll(__ballot(h1));
        }
    }

    // wave-level reduce of the 38 float accumulators (cnt already wave-uniform)
#pragma unroll
    for (int c = 0; c < CC; ++c) {
        for (int off = 32; off; off >>= 1) {
            accS[c] += __shfl_down(accS[c], off);
            accI[c] += __shfl_down(accI[c], off);
        }
    }

    __shared__ float s_part[4][64];
    const int wave = threadIdx.x >> 6;
    const int lane = threadIdx.x & 63;
    if (lane == 0) {
#pragma unroll
        for (int c = 0; c < CC; ++c) {
            s_part[wave][c]          = accS[c];
            s_part[wave][CC + c]     = accI[c];
            s_part[wave][2 * CC + c] = (float)cnt[c];
        }
#pragma unroll
        for (int c = 3 * CC; c < 64; ++c) s_part[wave][c] = 0.f;  // ws is poisoned
    }
    __syncthreads();
    if (threadIdx.x < 64) {
        float v = s_part[0][threadIdx.x] + s_part[1][threadIdx.x]
                + s_part[2][threadIdx.x] + s_part[3][threadIdx.x];
        part[blockIdx.x * 64 + threadIdx.x] = v;
    }
}

__global__ __launch_bounds__(1024) void dice_final(
    const float* __restrict__ part, float* __restrict__ out)
{
    const int wave = threadIdx.x >> 6;   // 0..15
    const int lane = threadIdx.x & 63;
    float v = 0.f;
    for (int r = wave; r < NBLK; r += 16)
        v += part[r * 64 + lane];        // coalesced 256B rows

    __shared__ float s_red[16][64];
    s_red[wave][lane] = v;
    __syncthreads();

    __shared__ float s_tot[64];
    if (threadIdx.x < 64) {
        float tot = 0.f;
#pragma unroll
        for (int w = 0; w < 16; ++w) tot += s_red[w][threadIdx.x];
        s_tot[threadIdx.x] = tot;
    }
    __syncthreads();

    if (threadIdx.x == 0) {
        float loss = 0.f, totv = 0.f;
#pragma unroll
        for (int c = 0; c < CC; ++c) {
            const float S = s_tot[c];
            const float I = s_tot[CC + c];
            const float N = s_tot[2 * CC + c];
            totv += N;
            loss += 1.f - (2.f * I + 1.f) / (S + N + 1.f);
        }
        out[0] = (totv > 0.f) ? loss * (1.f / (float)CC) : 0.f;
    }
}

extern "C" void kernel_launch(void* const* d_in, const int* in_sizes, int n_in,
                              void* d_out, int out_size, void* d_ws, size_t ws_size,
                              hipStream_t stream) {
    const float* logits = (const float*)d_in[0];
    const int* targets = (const int*)d_in[1];
    float* part = (float*)d_ws;          // 1024*64*4 = 256 KB
    float* out = (float*)d_out;

    dice_accum<<<NBLK, NTHR, 0, stream>>>(logits, targets, part);
    dice_final<<<1, 1024, 0, stream>>>(part, out);
}

// Round 4
// 254.987 us; speedup vs baseline: 1.0366x; 1.0366x over previous
//
#include <hip/hip_runtime.h>
#include <hip/hip_bf16.h>
#include <math.h>

// DiceLoss: B=8, C=19, H=W=512. logits fp32 [B,C,H,W], targets int [B,H,W].
// Round 4: LDS-tiled streaming. Stage 512-pixel x 19-channel tiles (38 KB)
// via cooperative float4 loads (1 KB/wave-instr -> request-rate relief),
// compute softmax stats from LDS (ds_read_b64, 2-way alias = free).
// No per-thread channel arrays in flight with loads -> no spills.

#define CC 19
#define HWBITS 18
#define HHWW (1 << HWBITS)            // 262144
#define NPIX (8 * HHWW)               // 2,097,152
#define TP 512                        // pixels per tile
#define TILEF4 (CC * TP / 4)          // 2432 float4 per tile
#define NBLK 1024
#define NTHR 256
#define TILES_PER_BLK 4               // 4096 tiles total
#define IGNORE_IDX 255

__global__ __launch_bounds__(NTHR) void dice_accum(
    const float* __restrict__ logits,
    const int* __restrict__ targets,
    float* __restrict__ part)         // part[NBLK][64]: 0-18 S, 19-37 I, 38-56 cnt
{
    __shared__ float xs[CC * TP];     // 38912 B tile: xs[c*TP + p]
    __shared__ float s_bins[2 * CC];  // [0..18]=inter, [19..37]=cnt
    __shared__ float s_part[4][64];

    const int tid = threadIdx.x;
    if (tid < 2 * CC) s_bins[tid] = 0.f;

    float accS[CC];
#pragma unroll
    for (int c = 0; c < CC; ++c) accS[c] = 0.f;

    for (int it = 0; it < TILES_PER_BLK; ++it) {
        const int tile = blockIdx.x * TILES_PER_BLK + it;
        const int p0 = tile * TP;                 // first pixel of tile
        const int b = p0 >> HWBITS;
        const int hw0 = p0 & (HHWW - 1);
        const float* bb = logits + ((size_t)(b * CC) << HWBITS) + hw0;

        __syncthreads();                          // xs safe to overwrite
        // ---- stage tile: 2432 float4, c-major rows of 128 float4 ----
        for (int j = tid; j < TILEF4; j += NTHR) {
            const int c = j >> 7;                 // j / 128
            const int o4 = j & 127;
            const float4 v = *(const float4*)(bb + ((size_t)c << HWBITS) + o4 * 4);
            *(float4*)&xs[j * 4] = v;             // xs[c*TP + o4*4]
        }
        const int2 tt = *(const int2*)(targets + p0 + 2 * tid);
        __syncthreads();

        // ---- sweep 1: exp-sums for this thread's 2 pixels ----
        float s0 = 0.f, s1 = 0.f;
#pragma unroll
        for (int c = 0; c < CC; ++c) {
            const float2 v = *(const float2*)&xs[c * TP + 2 * tid];
            s0 += __expf(v.x);
            s1 += __expf(v.y);
        }
        const bool v0 = (tt.x != IGNORE_IDX);
        const bool v1 = (tt.y != IGNORE_IDX);
        const float inv0 = v0 ? __builtin_amdgcn_rcpf(s0) : 0.f;
        const float inv1 = v1 ? __builtin_amdgcn_rcpf(s1) : 0.f;

        // ---- sweep 2: per-class prob sums (exp recomputed, trans pipe) ----
#pragma unroll
        for (int c = 0; c < CC; ++c) {
            const float2 v = *(const float2*)&xs[c * TP + 2 * tid];
            accS[c] = fmaf(__expf(v.x), inv0, accS[c]);
            accS[c] = fmaf(__expf(v.y), inv1, accS[c]);
        }

        // ---- gathered prob at true class + counts: LDS bins ----
        if (v0) {
            const float pt = __expf(xs[tt.x * TP + 2 * tid]) * inv0;
            atomicAdd(&s_bins[tt.x], pt);
            atomicAdd(&s_bins[CC + tt.x], 1.f);
        }
        if (v1) {
            const float pt = __expf(xs[tt.y * TP + 2 * tid + 1]) * inv1;
            atomicAdd(&s_bins[tt.y], pt);
            atomicAdd(&s_bins[CC + tt.y], 1.f);
        }
    }

    // ---- wave-reduce accS, then block partials ----
#pragma unroll
    for (int c = 0; c < CC; ++c) {
        for (int off = 32; off; off >>= 1)
            accS[c] += __shfl_down(accS[c], off);
    }
    const int wave = tid >> 6;
    const int lane = tid & 63;
    if (lane == 0) {
#pragma unroll
        for (int c = 0; c < CC; ++c) s_part[wave][c] = accS[c];
#pragma unroll
        for (int c = CC; c < 64; ++c) s_part[wave][c] = 0.f;
    }
    __syncthreads();
    if (tid < 64) {
        float v = s_part[0][tid] + s_part[1][tid]
                + s_part[2][tid] + s_part[3][tid];
        if (tid >= CC && tid < 3 * CC)            // cols 19..56 <- bins
            v += s_bins[tid - CC];                // inter at 19.., cnt at 38..
        part[blockIdx.x * 64 + tid] = v;
    }
}

__global__ __launch_bounds__(1024) void dice_final(
    const float* __restrict__ part, float* __restrict__ out)
{
    const int wave = threadIdx.x >> 6;   // 0..15
    const int lane = threadIdx.x & 63;
    float v = 0.f;
    for (int r = wave; r < NBLK; r += 16)
        v += part[r * 64 + lane];        // coalesced 256B rows

    __shared__ float s_red[16][64];
    s_red[wave][lane] = v;
    __syncthreads();

    __shared__ float s_tot[64];
    if (threadIdx.x < 64) {
        float tot = 0.f;
#pragma unroll
        for (int w = 0; w < 16; ++w) tot += s_red[w][threadIdx.x];
        s_tot[threadIdx.x] = tot;
    }
    __syncthreads();

    if (threadIdx.x == 0) {
        float loss = 0.f, totv = 0.f;
#pragma unroll
        for (int c = 0; c < CC; ++c) {
            const float S = s_tot[c];
            const float I = s_tot[CC + c];
            const float N = s_tot[2 * CC + c];
            totv += N;
            loss += 1.f - (2.f * I + 1.f) / (S + N + 1.f);
        }
        out[0] = (totv > 0.f) ? loss * (1.f / (float)CC) : 0.f;
    }
}

extern "C" void kernel_launch(void* const* d_in, const int* in_sizes, int n_in,
                              void* d_out, int out_size, void* d_ws, size_t ws_size,
                              hipStream_t stream) {
    const float* logits = (const float*)d_in[0];
    const int* targets = (const int*)d_in[1];
    float* part = (float*)d_ws;          // 1024*64*4 = 256 KB
    float* out = (float*)d_out;

    dice_accum<<<NBLK, NTHR, 0, stream>>>(logits, targets, part);
    dice_final<<<1, 1024, 0, stream>>>(part, out);
}

// Round 5
// 242.978 us; speedup vs baseline: 1.0878x; 1.0494x over previous
//
#include <hip/hip_runtime.h>
#include <hip/hip_bf16.h>
#include <math.h>

// DiceLoss: B=8, C=19, H=W=512. logits fp32 [B,C,H,W], targets int [B,H,W].
// Round 5: bytes-in-flight attack. Register-only hot loop: 19 batched float4
// loads (1 KB/wave-request, one vmcnt region, ~19 KB in flight per wave),
// 4 pixels/thread, no LDS / no atomics / no ballots (counts fused via the
// same t==c compare as intersection). 256-VGPR cap -> no spill, 2 iters.

#define CC 19
#define HWBITS 18
#define HHWW (1 << HWBITS)            // 262144
#define NPIX (8 * HHWW)               // 2,097,152
#define QPP (HHWW / 4)                // 65536 float4-quads per channel plane
#define NQUAD (NPIX / 4)              // 524288
#define NBLK 1024
#define NTHR 256
#define NTH_TOT (NBLK * NTHR)         // 262144
#define NITER (NQUAD / NTH_TOT)       // 2, exact
#define IGNORE_IDX 255

__global__ __launch_bounds__(NTHR, 2) void dice_accum(
    const float* __restrict__ logits,
    const int* __restrict__ targets,
    float* __restrict__ part)         // part[NBLK][64]: 0-18 S, 19-37 I, 38-56 cnt
{
    const int tid = blockIdx.x * NTHR + threadIdx.x;

    float accS[CC], accI[CC], accC[CC];
#pragma unroll
    for (int c = 0; c < CC; ++c) { accS[c] = 0.f; accI[c] = 0.f; accC[c] = 0.f; }

#pragma unroll 1                      // do NOT unroll: keeps x[] live set to one iter
    for (int it = 0; it < NITER; ++it) {
        const int q = tid + it * NTH_TOT;         // quad index
        const int b = q >> 16;                    // q / QPP
        const int hw4 = q & (QPP - 1);
        const float4* base = (const float4*)logits + (size_t)(b * CC) * QPP + hw4;

        // ---- Phase A: 19 independent dwordx4 loads, no consumers between ----
        float4 x[CC];
#pragma unroll
        for (int c = 0; c < CC; ++c)
            x[c] = base[(size_t)c * QPP];
        const int4 tt = *(const int4*)(targets + 4 * (size_t)q);

        // ---- Phase B: exp + per-pixel denominators ----
        float s0 = 0.f, s1 = 0.f, s2 = 0.f, s3 = 0.f;
#pragma unroll
        for (int c = 0; c < CC; ++c) {
            x[c].x = __expf(x[c].x); s0 += x[c].x;
            x[c].y = __expf(x[c].y); s1 += x[c].y;
            x[c].z = __expf(x[c].z); s2 += x[c].z;
            x[c].w = __expf(x[c].w); s3 += x[c].w;
        }
        const float i0 = (tt.x != IGNORE_IDX) ? __builtin_amdgcn_rcpf(s0) : 0.f;
        const float i1 = (tt.y != IGNORE_IDX) ? __builtin_amdgcn_rcpf(s1) : 0.f;
        const float i2 = (tt.z != IGNORE_IDX) ? __builtin_amdgcn_rcpf(s2) : 0.f;
        const float i3 = (tt.w != IGNORE_IDX) ? __builtin_amdgcn_rcpf(s3) : 0.f;

        // ---- Phase C: accumulate (pure VALU, compares shared by I and C) ----
#pragma unroll
        for (int c = 0; c < CC; ++c) {
            accS[c] = fmaf(x[c].x, i0,
                      fmaf(x[c].y, i1,
                      fmaf(x[c].z, i2,
                      fmaf(x[c].w, i3, accS[c]))));
            const bool h0 = (tt.x == c), h1 = (tt.y == c);
            const bool h2 = (tt.z == c), h3 = (tt.w == c);
            accI[c] = fmaf(h0 ? x[c].x : 0.f, i0,
                      fmaf(h1 ? x[c].y : 0.f, i1,
                      fmaf(h2 ? x[c].z : 0.f, i2,
                      fmaf(h3 ? x[c].w : 0.f, i3, accI[c]))));
            accC[c] += (h0 ? 1.f : 0.f) + (h1 ? 1.f : 0.f)
                     + (h2 ? 1.f : 0.f) + (h3 ? 1.f : 0.f);
        }
    }

    // ---- wave-level reduce of the 57 accumulators ----
#pragma unroll
    for (int c = 0; c < CC; ++c) {
        for (int off = 32; off; off >>= 1) {
            accS[c] += __shfl_down(accS[c], off);
            accI[c] += __shfl_down(accI[c], off);
            accC[c] += __shfl_down(accC[c], off);
        }
    }

    __shared__ float s_part[4][64];
    const int wave = threadIdx.x >> 6;
    const int lane = threadIdx.x & 63;
    if (lane == 0) {
#pragma unroll
        for (int c = 0; c < CC; ++c) {
            s_part[wave][c]          = accS[c];
            s_part[wave][CC + c]     = accI[c];
            s_part[wave][2 * CC + c] = accC[c];
        }
#pragma unroll
        for (int c = 3 * CC; c < 64; ++c) s_part[wave][c] = 0.f;  // ws is poisoned
    }
    __syncthreads();
    if (threadIdx.x < 64) {
        float v = s_part[0][threadIdx.x] + s_part[1][threadIdx.x]
                + s_part[2][threadIdx.x] + s_part[3][threadIdx.x];
        part[blockIdx.x * 64 + threadIdx.x] = v;
    }
}

__global__ __launch_bounds__(1024) void dice_final(
    const float* __restrict__ part, float* __restrict__ out)
{
    const int wave = threadIdx.x >> 6;   // 0..15
    const int lane = threadIdx.x & 63;
    float v = 0.f;
    for (int r = wave; r < NBLK; r += 16)
        v += part[r * 64 + lane];        // coalesced 256B rows

    __shared__ float s_red[16][64];
    s_red[wave][lane] = v;
    __syncthreads();

    __shared__ float s_tot[64];
    if (threadIdx.x < 64) {
        float tot = 0.f;
#pragma unroll
        for (int w = 0; w < 16; ++w) tot += s_red[w][threadIdx.x];
        s_tot[threadIdx.x] = tot;
    }
    __syncthreads();

    if (threadIdx.x == 0) {
        float loss = 0.f, totv = 0.f;
#pragma unroll
        for (int c = 0; c < CC; ++c) {
            const float S = s_tot[c];
            const float I = s_tot[CC + c];
            const float N = s_tot[2 * CC + c];
            totv += N;
            loss += 1.f - (2.f * I + 1.f) / (S + N + 1.f);
        }
        out[0] = (totv > 0.f) ? loss * (1.f / (float)CC) : 0.f;
    }
}

extern "C" void kernel_launch(void* const* d_in, const int* in_sizes, int n_in,
                              void* d_out, int out_size, void* d_ws, size_t ws_size,
                              hipStream_t stream) {
    const float* logits = (const float*)d_in[0];
    const int* targets = (const int*)d_in[1];
    float* part = (float*)d_ws;          // 1024*64*4 = 256 KB
    float* out = (float*)d_out;

    dice_accum<<<NBLK, NTHR, 0, stream>>>(logits, targets, part);
    dice_final<<<1, 1024, 0, stream>>>(part, out);
}